// Round 3
// baseline (274.606 us; speedup 1.0000x reference)
//
#include <hip/hip_runtime.h>

#define D_MODEL 512
#define DFF 2048
#define NEXP 8
#define LTOK 4096          // B*N tokens
#define NPAIR 8192         // LTOK * K
#define PMAX 9216          // padded gathered rows (8192 + 8*128)
#define MAXT 72            // max M-tiles

// hdr (int) offsets within ws
#define HD_COUNTS 0
#define HD_CURSOR 8
#define HD_OFF    16
#define HD_NTILES 25
#define HD_TILE_E 32
#define HD_TILE_R 112

// compile-verified gfx950 fragment types (guide §3): 8 bf16 carried as short8
typedef __attribute__((ext_vector_type(8))) short bf16x8;
typedef __attribute__((ext_vector_type(4))) float f32x4;

__device__ __forceinline__ unsigned short f2bf(float f){
  unsigned u = __builtin_bit_cast(unsigned, f);
  u += 0x7fffu + ((u>>16)&1u);        // RNE round to bf16
  return (unsigned short)(u>>16);
}

// ---------------- router: fp64 logits, top-2, weights, counts ----------------
__global__ void router_top2(const float* __restrict__ x, const float* __restrict__ rw,
                            int* __restrict__ hdr, int* __restrict__ pair_e,
                            float* __restrict__ pair_w){
  int t = blockIdx.x;
  int l = threadIdx.x;
  const float* xr = x + (size_t)t*D_MODEL;
  float xv[8];
  #pragma unroll
  for (int j=0;j<8;j++) xv[j] = xr[j*64+l];
  double lg[NEXP];
  #pragma unroll
  for (int e=0;e<NEXP;e++){
    const float* we = rw + e*D_MODEL;
    double s = 0.0;
    #pragma unroll
    for (int j=0;j<8;j++) s += (double)xv[j] * (double)we[j*64+l];
    #pragma unroll
    for (int off=32; off; off>>=1) s += __shfl_xor(s, off);
    lg[e] = s;
  }
  if (l==0){
    double mx = lg[0];
    #pragma unroll
    for (int e=1;e<NEXP;e++) if (lg[e]>mx) mx = lg[e];
    double p[NEXP], sum = 0.0;
    #pragma unroll
    for (int e=0;e<NEXP;e++){ p[e] = exp(lg[e]-mx); sum += p[e]; }
    #pragma unroll
    for (int e=0;e<NEXP;e++) p[e] /= sum;
    int i0 = 0;
    for (int e=1;e<NEXP;e++) if (p[e] > p[i0]) i0 = e;        // ties -> lower idx
    int i1 = (i0==0) ? 1 : 0;
    for (int e=0;e<NEXP;e++){ if (e==i0) continue; if (p[e] > p[i1]) i1 = e; }
    double s2 = p[i0] + p[i1] + 1e-9;
    pair_e[2*t]   = i0;  pair_e[2*t+1] = i1;
    pair_w[2*t]   = (float)(p[i0]/s2);
    pair_w[2*t+1] = (float)(p[i1]/s2);
    atomicAdd(&hdr[HD_COUNTS+i0], 1);
    atomicAdd(&hdr[HD_COUNTS+i1], 1);
  }
}

// ---------------- plan: padded offsets + tile table + defaults ----------------
__global__ void plan_kernel(int* __restrict__ hdr, int* __restrict__ gtok,
                            int* __restrict__ gtk){
  if (threadIdx.x==0){
    int off=0, nt=0;
    for (int e=0;e<NEXP;e++){
      hdr[HD_OFF+e]=off;
      int c = hdr[HD_COUNTS+e];
      int tiles = (c+127)>>7;
      for (int i=0;i<tiles;i++){ hdr[HD_TILE_E+nt]=e; hdr[HD_TILE_R+nt]=off+(i<<7); nt++; }
      off += tiles<<7;
    }
    hdr[HD_OFF+NEXP]=off;
    hdr[HD_NTILES]=nt;
  }
  for (int i=threadIdx.x; i<PMAX; i+=blockDim.x){ gtok[i]=0; gtk[i]=-1; }
}

// ---------------- assign each (token,slot) pair a gathered row ----------------
__global__ void assign_kernel(const int* __restrict__ pair_e, int* __restrict__ hdr,
                              int* __restrict__ gtok, int* __restrict__ gtk){
  int id = blockIdx.x*256 + threadIdx.x;
  if (id >= NPAIR) return;
  int e = pair_e[id];
  int r = atomicAdd(&hdr[HD_CURSOR+e], 1);
  int row = hdr[HD_OFF+e] + r;
  gtok[row] = id>>1;
  gtk[row]  = id;
}

// ---------------- gather x rows -> bf16 ----------------
__global__ void gather_x_kernel(const float* __restrict__ x, const int* __restrict__ gtok,
                                unsigned short* __restrict__ xg){
  int id = blockIdx.x*256 + threadIdx.x;     // one per 8 elements
  if (id >= PMAX*(D_MODEL/8)) return;
  int row = id>>6, j = id&63;
  int t = gtok[row];
  const float4* s = (const float4*)(x + (size_t)t*D_MODEL + j*8);
  float4 a = s[0], b = s[1];
  uint4 o;
  o.x = (unsigned)f2bf(a.x) | ((unsigned)f2bf(a.y)<<16);
  o.y = (unsigned)f2bf(a.z) | ((unsigned)f2bf(a.w)<<16);
  o.z = (unsigned)f2bf(b.x) | ((unsigned)f2bf(b.y)<<16);
  o.w = (unsigned)f2bf(b.z) | ((unsigned)f2bf(b.w)<<16);
  *(uint4*)(xg + (size_t)id*8) = o;
}

// ---------------- convert w1,w2 fp32 -> bf16 ----------------
__global__ void convw_kernel(const float* __restrict__ w1, const float* __restrict__ w2,
                             unsigned short* __restrict__ w1b, unsigned short* __restrict__ w2b){
  int id = blockIdx.x*256 + threadIdx.x;     // one per 8 elements
  const int per = NEXP*DFF*D_MODEL/8;        // 1048576
  const float* src; unsigned short* dst; int k;
  if (id < per){ src = w1; dst = w1b; k = id; }
  else         { src = w2; dst = w2b; k = id - per; }
  const float4* s = (const float4*)(src + (size_t)k*8);
  float4 a = s[0], b = s[1];
  uint4 o;
  o.x = (unsigned)f2bf(a.x) | ((unsigned)f2bf(a.y)<<16);
  o.y = (unsigned)f2bf(a.z) | ((unsigned)f2bf(a.w)<<16);
  o.z = (unsigned)f2bf(b.x) | ((unsigned)f2bf(b.y)<<16);
  o.w = (unsigned)f2bf(b.z) | ((unsigned)f2bf(b.w)<<16);
  *(uint4*)(dst + (size_t)k*8) = o;
}

// ---------------- grouped GEMM: 128x128 tile, BK=64, 16x16x32 bf16 MFMA ------
// A [PMAX][KDIM] bf16 row-major; Bw [NEXP][NDIM][KDIM] bf16 (B^T form).
// MODE 0: outH = relu(acc+bias) as bf16
// MODE 1: atomicAdd(out[token], pair_w * (acc+bias))  (fp32, 2 adds/elem -> deterministic)
template<int NDIM, int KDIM, int MODE>
__global__ __launch_bounds__(256,2) void gemm_moe(
    const unsigned short* __restrict__ A,
    const unsigned short* __restrict__ Bw,
    const float* __restrict__ bias,
    unsigned short* __restrict__ outH,
    float* __restrict__ outO,
    const float* __restrict__ pair_w,
    const int* __restrict__ hdr,
    const int* __restrict__ gtk)
{
  __shared__ __align__(16) unsigned short As[128*64];
  __shared__ __align__(16) unsigned short Bs[128*64];
  int bx = blockIdx.x;
  if (bx >= hdr[HD_NTILES]) return;
  int e    = hdr[HD_TILE_E+bx];
  int row0 = hdr[HD_TILE_R+bx];
  int n0   = blockIdx.y<<7;
  int tid  = threadIdx.x;
  int w = tid>>6, l = tid&63;
  int wm = w>>1, wn = w&1;

  const unsigned short* Ag = A  + (size_t)row0*KDIM;
  const unsigned short* Bg = Bw + (size_t)e*NDIM*KDIM + (size_t)n0*KDIM;

  f32x4 acc[4][4];
  f32x4 zz = {0.f,0.f,0.f,0.f};
  #pragma unroll
  for (int i=0;i<4;i++)
    #pragma unroll
    for (int j=0;j<4;j++) acc[i][j] = zz;

  int srow = (w<<3) + (l>>3);     // 0..31 within a 32-row issue
  int c8   = l&7;                 // 16B chunk within 128B row
  char* AsB = (char*)As;
  char* BsB = (char*)Bs;

  for (int kt=0; kt<KDIM/64; ++kt){
    #pragma unroll
    for (int i=0;i<4;i++){
      int r  = i*32 + srow;
      int sc = (c8 ^ (r&7))*8;                       // inverse-swizzled source chunk (elems)
      const unsigned short* ga = Ag + (size_t)r*KDIM + kt*64 + sc;
      const unsigned short* gb = Bg + (size_t)r*KDIM + kt*64 + sc;
      int ldso = i*4096 + w*1024 + l*16;             // linear LDS dest (bytes)
      __builtin_amdgcn_global_load_lds((const __attribute__((address_space(1))) void*)ga,
                                       (__attribute__((address_space(3))) void*)(AsB + ldso), 16, 0, 0);
      __builtin_amdgcn_global_load_lds((const __attribute__((address_space(1))) void*)gb,
                                       (__attribute__((address_space(3))) void*)(BsB + ldso), 16, 0, 0);
    }
    __syncthreads();
    #pragma unroll
    for (int kk=0;kk<2;kk++){
      bf16x8 av[4], bv[4];
      #pragma unroll
      for (int mi=0;mi<4;mi++){
        int r  = (wm<<6) + (mi<<4) + (l&15);
        int ch = ((kk<<2) + (l>>4)) ^ (r&7);         // swizzled read chunk
        av[mi] = *(const bf16x8*)(AsB + r*128 + ch*16);
      }
      #pragma unroll
      for (int ni=0;ni<4;ni++){
        int r  = (wn<<6) + (ni<<4) + (l&15);
        int ch = ((kk<<2) + (l>>4)) ^ (r&7);
        bv[ni] = *(const bf16x8*)(BsB + r*128 + ch*16);
      }
      #pragma unroll
      for (int mi=0;mi<4;mi++)
        #pragma unroll
        for (int ni=0;ni<4;ni++)
          acc[mi][ni] = __builtin_amdgcn_mfma_f32_16x16x32_bf16(av[mi], bv[ni], acc[mi][ni], 0,0,0);
    }
    __syncthreads();
  }

  int lc = l&15, lq = l>>4;
  #pragma unroll
  for (int ni=0;ni<4;ni++){
    int col = n0 + (wn<<6) + (ni<<4) + lc;
    float bcol = bias[e*NDIM + col];
    #pragma unroll
    for (int mi=0;mi<4;mi++){
      int rbase = row0 + (wm<<6) + (mi<<4) + lq*4;
      #pragma unroll
      for (int q=0;q<4;q++){
        int gr = rbase + q;
        float v = acc[mi][ni][q] + bcol;
        if (MODE==0){
          v = v>0.f ? v : 0.f;
          outH[(size_t)gr*NDIM + col] = f2bf(v);
        } else {
          int tk = gtk[gr];
          if (tk>=0){
            float wgt = pair_w[tk];
            atomicAdd(&outO[(size_t)(tk>>1)*D_MODEL + col], wgt*v);
          }
        }
      }
    }
  }
}

extern "C" void kernel_launch(void* const* d_in, const int* in_sizes, int n_in,
                              void* d_out, int out_size, void* d_ws, size_t ws_size,
                              hipStream_t stream){
  const float* x  = (const float*)d_in[0];
  const float* rw = (const float*)d_in[1];
  const float* w1 = (const float*)d_in[2];
  const float* b1 = (const float*)d_in[3];
  const float* w2 = (const float*)d_in[4];
  const float* b2 = (const float*)d_in[5];
  float* out = (float*)d_out;

  // ws layout (bytes):
  const size_t OFF_HDR  = 0;
  const size_t OFF_PE   = 1024;
  const size_t OFF_PW   = 66560;
  const size_t OFF_GTOK = 99328;
  const size_t OFF_GTK  = 136192;
  const size_t OFF_XG   = 180224;                          //  9.4 MB
  const size_t OFF_W1B  = OFF_XG  + (size_t)PMAX*D_MODEL*2;        // +9,437,184
  const size_t OFF_W2B  = OFF_W1B + (size_t)NEXP*DFF*D_MODEL*2;    // +16,777,216
  const size_t OFF_H    = OFF_W2B + (size_t)NEXP*DFF*D_MODEL*2;    // +16,777,216
  const size_t WS_NEED  = OFF_H   + (size_t)PMAX*DFF*2;            // +37,748,736 = ~80.9 MB
  if (ws_size < WS_NEED) return;   // refuse to scribble OOB (fails absmax cleanly)

  char* ws = (char*)d_ws;
  int*   hdr    = (int*)(ws + OFF_HDR);
  int*   pair_e = (int*)(ws + OFF_PE);
  float* pair_w = (float*)(ws + OFF_PW);
  int*   gtok   = (int*)(ws + OFF_GTOK);
  int*   gtk    = (int*)(ws + OFF_GTK);
  unsigned short* xg  = (unsigned short*)(ws + OFF_XG);
  unsigned short* w1b = (unsigned short*)(ws + OFF_W1B);
  unsigned short* w2b = (unsigned short*)(ws + OFF_W2B);
  unsigned short* h   = (unsigned short*)(ws + OFF_H);

  hipMemsetAsync(hdr, 0, 1024, stream);
  hipMemsetAsync(out, 0, (size_t)LTOK*D_MODEL*sizeof(float), stream);
  router_top2<<<LTOK, 64, 0, stream>>>(x, rw, hdr, pair_e, pair_w);
  plan_kernel<<<1, 256, 0, stream>>>(hdr, gtok, gtk);
  assign_kernel<<<NPAIR/256, 256, 0, stream>>>(pair_e, hdr, gtok, gtk);
  gather_x_kernel<<<(PMAX*64)/256, 256, 0, stream>>>(x, gtok, xg);
  convw_kernel<<<8192, 256, 0, stream>>>(w1, w2, w1b, w2b);
  gemm_moe<DFF, D_MODEL, 0><<<dim3(MAXT,16), 256, 0, stream>>>(xg, w1b, b1, h, nullptr, nullptr, hdr, gtk);
  gemm_moe<D_MODEL, DFF, 1><<<dim3(MAXT,4), 256, 0, stream>>>(h, w2b, b2, nullptr, out, pair_w, hdr, gtk);
}

// Round 4
// 154.003 us; speedup vs baseline: 1.7831x; 1.7831x over previous
//
#include <hip/hip_runtime.h>

#define D_MODEL 512
#define DFF 2048
#define NEXP 8
#define LTOK 4096          // B*N tokens
#define NPAIR 8192         // LTOK * K
#define PMAX 9216          // padded gathered rows (8192 + 8*128)
#define MAXT 72            // max M-tiles

// hdr (int) offsets within ws
#define HD_COUNTS 0
#define HD_CURSOR 8
#define HD_OFF    16
#define HD_NTILES 25
#define HD_TILE_E 32
#define HD_TILE_R 112

// compile-verified gfx950 fragment types (guide §3): 8 bf16 carried as short8
typedef __attribute__((ext_vector_type(8))) short bf16x8;
typedef __attribute__((ext_vector_type(4))) float f32x4;

__device__ __forceinline__ unsigned short f2bf(float f){
  unsigned u = __builtin_bit_cast(unsigned, f);
  u += 0x7fffu + ((u>>16)&1u);        // RNE round to bf16
  return (unsigned short)(u>>16);
}

// ---------------- router: fp64 logits, top-2, weights (NO atomics) ----------------
__global__ void router_top2(const float* __restrict__ x, const float* __restrict__ rw,
                            int* __restrict__ pair_e, float* __restrict__ pair_w){
  int t = blockIdx.x;
  int l = threadIdx.x;
  const float* xr = x + (size_t)t*D_MODEL;
  float xv[8];
  #pragma unroll
  for (int j=0;j<8;j++) xv[j] = xr[j*64+l];
  double lg[NEXP];
  #pragma unroll
  for (int e=0;e<NEXP;e++){
    const float* we = rw + e*D_MODEL;
    double s = 0.0;
    #pragma unroll
    for (int j=0;j<8;j++) s += (double)xv[j] * (double)we[j*64+l];
    #pragma unroll
    for (int off=32; off; off>>=1) s += __shfl_xor(s, off);
    lg[e] = s;
  }
  if (l==0){
    double mx = lg[0];
    #pragma unroll
    for (int e=1;e<NEXP;e++) if (lg[e]>mx) mx = lg[e];
    double p[NEXP], sum = 0.0;
    #pragma unroll
    for (int e=0;e<NEXP;e++){ p[e] = exp(lg[e]-mx); sum += p[e]; }
    #pragma unroll
    for (int e=0;e<NEXP;e++) p[e] /= sum;
    int i0 = 0;
    for (int e=1;e<NEXP;e++) if (p[e] > p[i0]) i0 = e;        // ties -> lower idx
    int i1 = (i0==0) ? 1 : 0;
    for (int e=0;e<NEXP;e++){ if (e==i0) continue; if (p[e] > p[i1]) i1 = e; }
    double s2 = p[i0] + p[i1] + 1e-9;
    pair_e[2*t]   = i0;  pair_e[2*t+1] = i1;
    pair_w[2*t]   = (float)(p[i0]/s2);
    pair_w[2*t+1] = (float)(p[i1]/s2);
  }
}

// ---------------- count: LDS histogram, 8 global atomics per block ----------------
__global__ void count_kernel(const int* __restrict__ pair_e, int* __restrict__ hdr){
  __shared__ int cnt[NEXP];
  int tid = threadIdx.x;
  if (tid < NEXP) cnt[tid] = 0;
  __syncthreads();
  int base = blockIdx.x*1024;
  #pragma unroll
  for (int i=0;i<4;i++) atomicAdd(&cnt[pair_e[base + i*256 + tid]], 1);
  __syncthreads();
  if (tid < NEXP) atomicAdd(&hdr[HD_COUNTS+tid], cnt[tid]);
}

// ---------------- plan: padded offsets + tile table + defaults ----------------
__global__ void plan_kernel(int* __restrict__ hdr, int* __restrict__ gtok,
                            int* __restrict__ gtk){
  if (threadIdx.x==0){
    int off=0, nt=0;
    for (int e=0;e<NEXP;e++){
      hdr[HD_OFF+e]=off;
      int c = hdr[HD_COUNTS+e];
      int tiles = (c+127)>>7;
      for (int i=0;i<tiles;i++){ hdr[HD_TILE_E+nt]=e; hdr[HD_TILE_R+nt]=off+(i<<7); nt++; }
      off += tiles<<7;
    }
    hdr[HD_OFF+NEXP]=off;
    hdr[HD_NTILES]=nt;
  }
  for (int i=threadIdx.x; i<PMAX; i+=blockDim.x){ gtok[i]=0; gtk[i]=-1; }
}

// ---------------- assign: LDS rank + per-block range reservation ----------------
__global__ void assign_kernel(const int* __restrict__ pair_e, int* __restrict__ hdr,
                              int* __restrict__ gtok, int* __restrict__ gtk){
  __shared__ int cnt[NEXP];
  __shared__ int base[NEXP];
  int tid = threadIdx.x;
  if (tid < NEXP) cnt[tid] = 0;
  __syncthreads();
  int id = blockIdx.x*256 + tid;
  int e = pair_e[id];
  int myrank = atomicAdd(&cnt[e], 1);           // LDS atomic
  __syncthreads();
  if (tid < NEXP) base[tid] = atomicAdd(&hdr[HD_CURSOR+tid], cnt[tid]);  // 8 global/block
  __syncthreads();
  int row = hdr[HD_OFF+e] + base[e] + myrank;
  gtok[row] = id>>1;
  gtk[row]  = id;
}

// ---------------- gather x rows -> bf16 ----------------
__global__ void gather_x_kernel(const float* __restrict__ x, const int* __restrict__ gtok,
                                unsigned short* __restrict__ xg){
  int id = blockIdx.x*256 + threadIdx.x;     // one per 8 elements
  if (id >= PMAX*(D_MODEL/8)) return;
  int row = id>>6, j = id&63;
  int t = gtok[row];
  const float4* s = (const float4*)(x + (size_t)t*D_MODEL + j*8);
  float4 a = s[0], b = s[1];
  uint4 o;
  o.x = (unsigned)f2bf(a.x) | ((unsigned)f2bf(a.y)<<16);
  o.y = (unsigned)f2bf(a.z) | ((unsigned)f2bf(a.w)<<16);
  o.z = (unsigned)f2bf(b.x) | ((unsigned)f2bf(b.y)<<16);
  o.w = (unsigned)f2bf(b.z) | ((unsigned)f2bf(b.w)<<16);
  *(uint4*)(xg + (size_t)id*8) = o;
}

// ---------------- convert w1,w2 fp32 -> bf16 ----------------
__global__ void convw_kernel(const float* __restrict__ w1, const float* __restrict__ w2,
                             unsigned short* __restrict__ w1b, unsigned short* __restrict__ w2b){
  int id = blockIdx.x*256 + threadIdx.x;     // one per 8 elements
  const int per = NEXP*DFF*D_MODEL/8;        // 1048576
  const float* src; unsigned short* dst; int k;
  if (id < per){ src = w1; dst = w1b; k = id; }
  else         { src = w2; dst = w2b; k = id - per; }
  const float4* s = (const float4*)(src + (size_t)k*8);
  float4 a = s[0], b = s[1];
  uint4 o;
  o.x = (unsigned)f2bf(a.x) | ((unsigned)f2bf(a.y)<<16);
  o.y = (unsigned)f2bf(a.z) | ((unsigned)f2bf(a.w)<<16);
  o.z = (unsigned)f2bf(b.x) | ((unsigned)f2bf(b.y)<<16);
  o.w = (unsigned)f2bf(b.z) | ((unsigned)f2bf(b.w)<<16);
  *(uint4*)(dst + (size_t)k*8) = o;
}

// ---------------- grouped GEMM: 128x128 tile, BK=64, 16x16x32 bf16 MFMA ------
// A [PMAX][KDIM] bf16 row-major; Bw [NEXP][NDIM][KDIM] bf16 (B^T form).
// MODE 0: outH = relu(acc+bias) as bf16
// MODE 1: atomicAdd(out[token], pair_w * (acc+bias))  (fp32, 2 adds/elem -> deterministic)
template<int NDIM, int KDIM, int MODE>
__global__ __launch_bounds__(256,2) void gemm_moe(
    const unsigned short* __restrict__ A,
    const unsigned short* __restrict__ Bw,
    const float* __restrict__ bias,
    unsigned short* __restrict__ outH,
    float* __restrict__ outO,
    const float* __restrict__ pair_w,
    const int* __restrict__ hdr,
    const int* __restrict__ gtk)
{
  __shared__ __align__(16) unsigned short As[128*64];
  __shared__ __align__(16) unsigned short Bs[128*64];
  int bx = blockIdx.x;
  if (bx >= hdr[HD_NTILES]) return;
  int e    = hdr[HD_TILE_E+bx];
  int row0 = hdr[HD_TILE_R+bx];
  int n0   = blockIdx.y<<7;
  int tid  = threadIdx.x;
  int w = tid>>6, l = tid&63;
  int wm = w>>1, wn = w&1;

  const unsigned short* Ag = A  + (size_t)row0*KDIM;
  const unsigned short* Bg = Bw + (size_t)e*NDIM*KDIM + (size_t)n0*KDIM;

  f32x4 acc[4][4];
  f32x4 zz = {0.f,0.f,0.f,0.f};
  #pragma unroll
  for (int i=0;i<4;i++)
    #pragma unroll
    for (int j=0;j<4;j++) acc[i][j] = zz;

  int srow = (w<<3) + (l>>3);     // 0..31 within a 32-row issue
  int c8   = l&7;                 // 16B chunk within 128B row
  char* AsB = (char*)As;
  char* BsB = (char*)Bs;

  for (int kt=0; kt<KDIM/64; ++kt){
    #pragma unroll
    for (int i=0;i<4;i++){
      int r  = i*32 + srow;
      int sc = (c8 ^ (r&7))*8;                       // inverse-swizzled source chunk (elems)
      const unsigned short* ga = Ag + (size_t)r*KDIM + kt*64 + sc;
      const unsigned short* gb = Bg + (size_t)r*KDIM + kt*64 + sc;
      int ldso = i*4096 + w*1024 + l*16;             // linear LDS dest (bytes)
      __builtin_amdgcn_global_load_lds((const __attribute__((address_space(1))) void*)ga,
                                       (__attribute__((address_space(3))) void*)(AsB + ldso), 16, 0, 0);
      __builtin_amdgcn_global_load_lds((const __attribute__((address_space(1))) void*)gb,
                                       (__attribute__((address_space(3))) void*)(BsB + ldso), 16, 0, 0);
    }
    __syncthreads();
    #pragma unroll
    for (int kk=0;kk<2;kk++){
      bf16x8 av[4], bv[4];
      #pragma unroll
      for (int mi=0;mi<4;mi++){
        int r  = (wm<<6) + (mi<<4) + (l&15);
        int ch = ((kk<<2) + (l>>4)) ^ (r&7);         // swizzled read chunk
        av[mi] = *(const bf16x8*)(AsB + r*128 + ch*16);
      }
      #pragma unroll
      for (int ni=0;ni<4;ni++){
        int r  = (wn<<6) + (ni<<4) + (l&15);
        int ch = ((kk<<2) + (l>>4)) ^ (r&7);
        bv[ni] = *(const bf16x8*)(BsB + r*128 + ch*16);
      }
      #pragma unroll
      for (int mi=0;mi<4;mi++)
        #pragma unroll
        for (int ni=0;ni<4;ni++)
          acc[mi][ni] = __builtin_amdgcn_mfma_f32_16x16x32_bf16(av[mi], bv[ni], acc[mi][ni], 0,0,0);
    }
    __syncthreads();
  }

  int lc = l&15, lq = l>>4;
  #pragma unroll
  for (int ni=0;ni<4;ni++){
    int col = n0 + (wn<<6) + (ni<<4) + lc;
    float bcol = bias[e*NDIM + col];
    #pragma unroll
    for (int mi=0;mi<4;mi++){
      int rbase = row0 + (wm<<6) + (mi<<4) + lq*4;
      #pragma unroll
      for (int q=0;q<4;q++){
        int gr = rbase + q;
        float v = acc[mi][ni][q] + bcol;
        if (MODE==0){
          v = v>0.f ? v : 0.f;
          outH[(size_t)gr*NDIM + col] = f2bf(v);
        } else {
          int tk = gtk[gr];
          if (tk>=0){
            float wgt = pair_w[tk];
            atomicAdd(&outO[(size_t)(tk>>1)*D_MODEL + col], wgt*v);
          }
        }
      }
    }
  }
}

extern "C" void kernel_launch(void* const* d_in, const int* in_sizes, int n_in,
                              void* d_out, int out_size, void* d_ws, size_t ws_size,
                              hipStream_t stream){
  const float* x  = (const float*)d_in[0];
  const float* rw = (const float*)d_in[1];
  const float* w1 = (const float*)d_in[2];
  const float* b1 = (const float*)d_in[3];
  const float* w2 = (const float*)d_in[4];
  const float* b2 = (const float*)d_in[5];
  float* out = (float*)d_out;

  // ws layout (bytes):
  const size_t OFF_HDR  = 0;
  const size_t OFF_PE   = 1024;
  const size_t OFF_PW   = 66560;
  const size_t OFF_GTOK = 99328;
  const size_t OFF_GTK  = 136192;
  const size_t OFF_XG   = 180224;
  const size_t OFF_W1B  = OFF_XG  + (size_t)PMAX*D_MODEL*2;        // +9,437,184
  const size_t OFF_W2B  = OFF_W1B + (size_t)NEXP*DFF*D_MODEL*2;    // +16,777,216
  const size_t OFF_H    = OFF_W2B + (size_t)NEXP*DFF*D_MODEL*2;    // +16,777,216
  const size_t WS_NEED  = OFF_H   + (size_t)PMAX*DFF*2;            // +37,748,736 = ~80.9 MB
  if (ws_size < WS_NEED) return;   // refuse to scribble OOB (fails absmax cleanly)

  char* ws = (char*)d_ws;
  int*   hdr    = (int*)(ws + OFF_HDR);
  int*   pair_e = (int*)(ws + OFF_PE);
  float* pair_w = (float*)(ws + OFF_PW);
  int*   gtok   = (int*)(ws + OFF_GTOK);
  int*   gtk    = (int*)(ws + OFF_GTK);
  unsigned short* xg  = (unsigned short*)(ws + OFF_XG);
  unsigned short* w1b = (unsigned short*)(ws + OFF_W1B);
  unsigned short* w2b = (unsigned short*)(ws + OFF_W2B);
  unsigned short* h   = (unsigned short*)(ws + OFF_H);

  hipMemsetAsync(hdr, 0, 1024, stream);
  hipMemsetAsync(out, 0, (size_t)LTOK*D_MODEL*sizeof(float), stream);
  router_top2<<<LTOK, 64, 0, stream>>>(x, rw, pair_e, pair_w);
  count_kernel<<<NPAIR/1024, 256, 0, stream>>>(pair_e, hdr);
  plan_kernel<<<1, 256, 0, stream>>>(hdr, gtok, gtk);
  assign_kernel<<<NPAIR/256, 256, 0, stream>>>(pair_e, hdr, gtok, gtk);
  gather_x_kernel<<<(PMAX*64)/256, 256, 0, stream>>>(x, gtok, xg);
  convw_kernel<<<8192, 256, 0, stream>>>(w1, w2, w1b, w2b);
  gemm_moe<DFF, D_MODEL, 0><<<dim3(MAXT,16), 256, 0, stream>>>(xg, w1b, b1, h, nullptr, nullptr, hdr, gtk);
  gemm_moe<D_MODEL, DFF, 1><<<dim3(MAXT,4), 256, 0, stream>>>(h, w2b, b2, nullptr, out, pair_w, hdr, gtk);
}

// Round 5
// 127.694 us; speedup vs baseline: 2.1505x; 1.2060x over previous
//
#include <hip/hip_runtime.h>

#define D_MODEL 512
#define DFF 2048
#define NEXP 8
#define LTOK 4096          // B*N tokens
#define NPAIR 8192         // LTOK * K
#define PMAX 9216          // padded gathered rows (8192 + 8*128)
#define MAXT 72            // max 128-row M-tiles

// hdr (int) offsets within ws
#define HD_COUNTS 0
#define HD_CURSOR 8
#define HD_OFF    16
#define HD_NTILES 25
#define HD_TILE_E 32
#define HD_TILE_R 112

typedef __attribute__((ext_vector_type(8))) short bf16x8;
typedef __attribute__((ext_vector_type(4))) float f32x4;

__device__ __forceinline__ unsigned short f2bf(float f){
  unsigned u = __builtin_bit_cast(unsigned, f);
  u += 0x7fffu + ((u>>16)&1u);        // RNE round to bf16
  return (unsigned short)(u>>16);
}

template<int N> __device__ __forceinline__ void wait_vm(){
  if constexpr (N==8)      asm volatile("s_waitcnt vmcnt(8)" ::: "memory");
  else if constexpr (N==6) asm volatile("s_waitcnt vmcnt(6)" ::: "memory");
  else                     asm volatile("s_waitcnt vmcnt(0)" ::: "memory");
}
#define RAW_BARRIER() asm volatile("s_barrier" ::: "memory")

// ---------------- router: fp64 logits, top-2, weights (NO atomics) ----------------
__global__ void router_top2(const float* __restrict__ x, const float* __restrict__ rw,
                            int* __restrict__ pair_e, float* __restrict__ pair_w){
  int t = blockIdx.x;
  int l = threadIdx.x;
  const float* xr = x + (size_t)t*D_MODEL;
  float xv[8];
  #pragma unroll
  for (int j=0;j<8;j++) xv[j] = xr[j*64+l];
  double lg[NEXP];
  #pragma unroll
  for (int e=0;e<NEXP;e++){
    const float* we = rw + e*D_MODEL;
    double s = 0.0;
    #pragma unroll
    for (int j=0;j<8;j++) s += (double)xv[j] * (double)we[j*64+l];
    #pragma unroll
    for (int off=32; off; off>>=1) s += __shfl_xor(s, off);
    lg[e] = s;
  }
  if (l==0){
    double mx = lg[0];
    #pragma unroll
    for (int e=1;e<NEXP;e++) if (lg[e]>mx) mx = lg[e];
    double p[NEXP], sum = 0.0;
    #pragma unroll
    for (int e=0;e<NEXP;e++){ p[e] = exp(lg[e]-mx); sum += p[e]; }
    #pragma unroll
    for (int e=0;e<NEXP;e++) p[e] /= sum;
    int i0 = 0;
    for (int e=1;e<NEXP;e++) if (p[e] > p[i0]) i0 = e;        // ties -> lower idx
    int i1 = (i0==0) ? 1 : 0;
    for (int e=0;e<NEXP;e++){ if (e==i0) continue; if (p[e] > p[i1]) i1 = e; }
    double s2 = p[i0] + p[i1] + 1e-9;
    pair_e[2*t]   = i0;  pair_e[2*t+1] = i1;
    pair_w[2*t]   = (float)(p[i0]/s2);
    pair_w[2*t+1] = (float)(p[i1]/s2);
  }
}

// ---------------- count: LDS histogram, 8 global atomics per block ----------------
__global__ void count_kernel(const int* __restrict__ pair_e, int* __restrict__ hdr){
  __shared__ int cnt[NEXP];
  int tid = threadIdx.x;
  if (tid < NEXP) cnt[tid] = 0;
  __syncthreads();
  int base = blockIdx.x*1024;
  #pragma unroll
  for (int i=0;i<4;i++) atomicAdd(&cnt[pair_e[base + i*256 + tid]], 1);
  __syncthreads();
  if (tid < NEXP) atomicAdd(&hdr[HD_COUNTS+tid], cnt[tid]);
}

// ---------------- plan: padded offsets + tile table + defaults ----------------
__global__ void plan_kernel(int* __restrict__ hdr, int* __restrict__ gtok,
                            int* __restrict__ gtk){
  if (threadIdx.x==0){
    int off=0, nt=0;
    for (int e=0;e<NEXP;e++){
      hdr[HD_OFF+e]=off;
      int c = hdr[HD_COUNTS+e];
      int tiles = (c+127)>>7;
      for (int i=0;i<tiles;i++){ hdr[HD_TILE_E+nt]=e; hdr[HD_TILE_R+nt]=off+(i<<7); nt++; }
      off += tiles<<7;
    }
    hdr[HD_OFF+NEXP]=off;
    hdr[HD_NTILES]=nt;
  }
  for (int i=threadIdx.x; i<PMAX; i+=blockDim.x){ gtok[i]=0; gtk[i]=-1; }
}

// ---------------- assign: LDS rank + per-block range reservation ----------------
__global__ void assign_kernel(const int* __restrict__ pair_e, int* __restrict__ hdr,
                              int* __restrict__ gtok, int* __restrict__ gtk){
  __shared__ int cnt[NEXP];
  __shared__ int base[NEXP];
  int tid = threadIdx.x;
  if (tid < NEXP) cnt[tid] = 0;
  __syncthreads();
  int id = blockIdx.x*256 + tid;
  int e = pair_e[id];
  int myrank = atomicAdd(&cnt[e], 1);           // LDS atomic
  __syncthreads();
  if (tid < NEXP) base[tid] = atomicAdd(&hdr[HD_CURSOR+tid], cnt[tid]);  // 8 global/block
  __syncthreads();
  int row = hdr[HD_OFF+e] + base[e] + myrank;
  gtok[row] = id>>1;
  gtk[row]  = id;
}

// ---------------- gather x rows -> bf16 ----------------
__global__ void gather_x_kernel(const float* __restrict__ x, const int* __restrict__ gtok,
                                unsigned short* __restrict__ xg){
  int id = blockIdx.x*256 + threadIdx.x;     // one per 8 elements
  if (id >= PMAX*(D_MODEL/8)) return;
  int row = id>>6, j = id&63;
  int t = gtok[row];
  const float4* s = (const float4*)(x + (size_t)t*D_MODEL + j*8);
  float4 a = s[0], b = s[1];
  uint4 o;
  o.x = (unsigned)f2bf(a.x) | ((unsigned)f2bf(a.y)<<16);
  o.y = (unsigned)f2bf(a.z) | ((unsigned)f2bf(a.w)<<16);
  o.z = (unsigned)f2bf(b.x) | ((unsigned)f2bf(b.y)<<16);
  o.w = (unsigned)f2bf(b.z) | ((unsigned)f2bf(b.w)<<16);
  *(uint4*)(xg + (size_t)id*8) = o;
}

// ---------------- convert w1,w2 fp32 -> bf16 ----------------
__global__ void convw_kernel(const float* __restrict__ w1, const float* __restrict__ w2,
                             unsigned short* __restrict__ w1b, unsigned short* __restrict__ w2b){
  int id = blockIdx.x*256 + threadIdx.x;     // one per 8 elements
  const int per = NEXP*DFF*D_MODEL/8;        // 1048576
  const float* src; unsigned short* dst; int k;
  if (id < per){ src = w1; dst = w1b; k = id; }
  else         { src = w2; dst = w2b; k = id - per; }
  const float4* s = (const float4*)(src + (size_t)k*8);
  float4 a = s[0], b = s[1];
  uint4 o;
  o.x = (unsigned)f2bf(a.x) | ((unsigned)f2bf(a.y)<<16);
  o.y = (unsigned)f2bf(a.z) | ((unsigned)f2bf(a.w)<<16);
  o.z = (unsigned)f2bf(b.x) | ((unsigned)f2bf(b.y)<<16);
  o.w = (unsigned)f2bf(b.z) | ((unsigned)f2bf(b.w)<<16);
  *(uint4*)(dst + (size_t)k*8) = o;
}

// ---------------- grouped GEMM, 2-phase double-buffered pipeline -------------
// MT x 128 tile, BK=64, 4 waves. MT=128: 2x2 waves of 64x64. MT=64: 1x4 waves of 64x32.
// A [PMAX][KDIM] bf16; Bw [NEXP][NDIM][KDIM] bf16 (B^T). Both-sides XOR swizzle.
// Counted vmcnt keeps next tile's global_load_lds in flight across raw barriers.
// MODE 0: outH = relu(acc+bias) bf16    MODE 1: atomicAdd(out, pair_w*(acc+bias))
template<int MT, int NDIM, int KDIM, int MODE>
__global__ __launch_bounds__(256,2) void gemm2p(
    const unsigned short* __restrict__ A,
    const unsigned short* __restrict__ Bw,
    const float* __restrict__ bias,
    unsigned short* __restrict__ outH,
    float* __restrict__ outO,
    const float* __restrict__ pair_w,
    const int* __restrict__ hdr,
    const int* __restrict__ gtk)
{
  constexpr int NT_N = NDIM/128;               // N-tiles
  constexpr int MAXM = (MT==128) ? MAXT : 2*MAXT;
  constexpr int NWG  = MAXM*NT_N;              // 1152 or 576 (both %8==0)
  constexpr int WC   = (MT==128) ? 64 : 32;    // wave N-cols
  constexpr int FN   = WC/16;                  // N frags per wave
  constexpr int LPT  = MT/32 + 4;              // gload_lds per thread per K-step
  constexpr int ABYT = MT*128;                 // A buffer bytes
  constexpr int NTK  = KDIM/64;

  __shared__ __align__(16) unsigned short As[2*MT*64];
  __shared__ __align__(16) unsigned short Bs[2*128*64];

  // XCD-chunked bijective swizzle (NWG%8==0), N-fastest within chunk
  int wg  = blockIdx.x;
  int swz = (wg & 7)*(NWG/8) + (wg >> 3);
  int m   = swz / NT_N;
  int n0  = (swz % NT_N) << 7;

  int ntiles = hdr[HD_NTILES];
  int e, row0;
  if constexpr (MT==128){
    if (m >= ntiles) return;
    e = hdr[HD_TILE_E+m];  row0 = hdr[HD_TILE_R+m];
  } else {
    if (m >= 2*ntiles) return;
    e = hdr[HD_TILE_E+(m>>1)];  row0 = hdr[HD_TILE_R+(m>>1)] + ((m&1)<<6);
  }

  int tid = threadIdx.x;
  int w = tid>>6, l = tid&63;
  int wm = (MT==128) ? (w>>1) : 0;
  int wn = (MT==128) ? (w&1)  : w;

  const unsigned short* Ag = A  + (size_t)row0*KDIM;
  const unsigned short* Bg = Bw + (size_t)e*NDIM*KDIM + (size_t)n0*KDIM;

  f32x4 acc[4][FN];
  f32x4 zz = {0.f,0.f,0.f,0.f};
  #pragma unroll
  for (int i=0;i<4;i++)
    #pragma unroll
    for (int j=0;j<FN;j++) acc[i][j] = zz;

  int srow = (w<<3) + (l>>3);     // 0..31 within a 32-row issue
  int c8   = l&7;                 // 16B chunk within 128B row
  char* AsB = (char*)As;
  char* BsB = (char*)Bs;

  auto stage = [&](int b, int kt){
    #pragma unroll
    for (int i=0;i<MT/32;i++){
      int r  = i*32 + srow;
      int sc = (c8 ^ (r&7))*8;                       // inverse-swizzled source (elems)
      const unsigned short* ga = Ag + (size_t)r*KDIM + kt*64 + sc;
      int ldso = b*ABYT + i*4096 + w*1024 + l*16;    // linear LDS dest (bytes)
      __builtin_amdgcn_global_load_lds((const __attribute__((address_space(1))) void*)ga,
                                       (__attribute__((address_space(3))) void*)(AsB + ldso), 16, 0, 0);
    }
    #pragma unroll
    for (int i=0;i<4;i++){
      int r  = i*32 + srow;
      int sc = (c8 ^ (r&7))*8;
      const unsigned short* gb = Bg + (size_t)r*KDIM + kt*64 + sc;
      int ldso = b*16384 + i*4096 + w*1024 + l*16;
      __builtin_amdgcn_global_load_lds((const __attribute__((address_space(1))) void*)gb,
                                       (__attribute__((address_space(3))) void*)(BsB + ldso), 16, 0, 0);
    }
  };

  auto compute = [&](int b){
    #pragma unroll
    for (int kk=0;kk<2;kk++){
      bf16x8 av[4], bv[FN];
      #pragma unroll
      for (int mi=0;mi<4;mi++){
        int r  = (wm<<6) + (mi<<4) + (l&15);
        int ch = ((kk<<2) + (l>>4)) ^ (r&7);         // swizzled read chunk
        av[mi] = *(const bf16x8*)(AsB + b*ABYT + r*128 + ch*16);
      }
      #pragma unroll
      for (int ni=0;ni<FN;ni++){
        int r  = wn*WC + (ni<<4) + (l&15);
        int ch = ((kk<<2) + (l>>4)) ^ (r&7);
        bv[ni] = *(const bf16x8*)(BsB + b*16384 + r*128 + ch*16);
      }
      #pragma unroll
      for (int mi=0;mi<4;mi++)
        #pragma unroll
        for (int ni=0;ni<FN;ni++)
          acc[mi][ni] = __builtin_amdgcn_mfma_f32_16x16x32_bf16(av[mi], bv[ni], acc[mi][ni], 0,0,0);
    }
  };

  // ---- 2-phase pipeline: loads for tile kt+1 stay in flight across barriers ----
  stage(0, 0);
  int cur = 0;
  for (int kt=0; kt<NTK-1; ++kt){
    stage(cur^1, kt+1);
    wait_vm<LPT>();                 // own loads for buf[cur] done (newer LPT still flying)
    RAW_BARRIER();                  // => everyone's loads for buf[cur] done
    compute(cur);
    asm volatile("s_waitcnt lgkmcnt(0)" ::: "memory");
    RAW_BARRIER();                  // all reads of buf[cur] complete -> reusable
    cur ^= 1;
  }
  wait_vm<0>();
  RAW_BARRIER();
  compute(cur);

  int lc = l&15, lq = l>>4;
  #pragma unroll
  for (int ni=0;ni<FN;ni++){
    int col = n0 + wn*WC + (ni<<4) + lc;
    float bcol = bias[e*NDIM + col];
    #pragma unroll
    for (int mi=0;mi<4;mi++){
      int rbase = row0 + (wm<<6) + (mi<<4) + lq*4;
      #pragma unroll
      for (int q=0;q<4;q++){
        int gr = rbase + q;
        float v = acc[mi][ni][q] + bcol;
        if (MODE==0){
          v = v>0.f ? v : 0.f;
          outH[(size_t)gr*NDIM + col] = f2bf(v);
        } else {
          int tk = gtk[gr];
          if (tk>=0){
            float wgt = pair_w[tk];
            atomicAdd(&outO[(size_t)(tk>>1)*D_MODEL + col], wgt*v);
          }
        }
      }
    }
  }
}

extern "C" void kernel_launch(void* const* d_in, const int* in_sizes, int n_in,
                              void* d_out, int out_size, void* d_ws, size_t ws_size,
                              hipStream_t stream){
  const float* x  = (const float*)d_in[0];
  const float* rw = (const float*)d_in[1];
  const float* w1 = (const float*)d_in[2];
  const float* b1 = (const float*)d_in[3];
  const float* w2 = (const float*)d_in[4];
  const float* b2 = (const float*)d_in[5];
  float* out = (float*)d_out;

  // ws layout (bytes):
  const size_t OFF_HDR  = 0;
  const size_t OFF_PE   = 1024;
  const size_t OFF_PW   = 66560;
  const size_t OFF_GTOK = 99328;
  const size_t OFF_GTK  = 136192;
  const size_t OFF_XG   = 180224;
  const size_t OFF_W1B  = OFF_XG  + (size_t)PMAX*D_MODEL*2;        // +9,437,184
  const size_t OFF_W2B  = OFF_W1B + (size_t)NEXP*DFF*D_MODEL*2;    // +16,777,216
  const size_t OFF_H    = OFF_W2B + (size_t)NEXP*DFF*D_MODEL*2;    // +16,777,216
  const size_t WS_NEED  = OFF_H   + (size_t)PMAX*DFF*2;            // +37,748,736 = ~80.9 MB
  if (ws_size < WS_NEED) return;   // refuse to scribble OOB (fails absmax cleanly)

  char* ws = (char*)d_ws;
  int*   hdr    = (int*)(ws + OFF_HDR);
  int*   pair_e = (int*)(ws + OFF_PE);
  float* pair_w = (float*)(ws + OFF_PW);
  int*   gtok   = (int*)(ws + OFF_GTOK);
  int*   gtk    = (int*)(ws + OFF_GTK);
  unsigned short* xg  = (unsigned short*)(ws + OFF_XG);
  unsigned short* w1b = (unsigned short*)(ws + OFF_W1B);
  unsigned short* w2b = (unsigned short*)(ws + OFF_W2B);
  unsigned short* h   = (unsigned short*)(ws + OFF_H);

  hipMemsetAsync(hdr, 0, 1024, stream);
  hipMemsetAsync(out, 0, (size_t)LTOK*D_MODEL*sizeof(float), stream);
  router_top2<<<LTOK, 64, 0, stream>>>(x, rw, pair_e, pair_w);
  count_kernel<<<NPAIR/1024, 256, 0, stream>>>(pair_e, hdr);
  plan_kernel<<<1, 256, 0, stream>>>(hdr, gtok, gtk);
  assign_kernel<<<NPAIR/256, 256, 0, stream>>>(pair_e, hdr, gtok, gtk);
  gather_x_kernel<<<(PMAX*64)/256, 256, 0, stream>>>(x, gtok, xg);
  convw_kernel<<<8192, 256, 0, stream>>>(w1, w2, w1b, w2b);
  gemm2p<128, DFF, D_MODEL, 0><<<MAXT*16, 256, 0, stream>>>(xg, w1b, b1, h, nullptr, nullptr, hdr, gtk);
  gemm2p<64, D_MODEL, DFF, 1><<<2*MAXT*4, 256, 0, stream>>>(h, w2b, b2, nullptr, out, pair_w, hdr, gtk);
}